// Round 2
// baseline (157.188 us; speedup 1.0000x reference)
//
#include <hip/hip_runtime.h>

// K=128 users, M=1024, N=C=128.
// Fused kernel: each block (kp, slice) computes h = h_d + A·v for its own
//   2 users x 64 m-rows (nontemporal dwordx4, DPP sum16), stores h to LDS,
//   then runs the partial g = h @ W GEMM for that slice.
//   Phase 1 is explicitly software-pipelined 2-deep: iter i+1's 8 loads are
//   issued before iter i's data is consumed (64 data VGPRs, fits the
//   128-VGPR cap from __launch_bounds__(256,4)).
// rate_kernel: partials laid out [k][slice][c] (contiguous 16KB per user);
//   256 threads split the 16-slice reduction 8+8 to halve the load chain.

#define NSLICE 16
#define MSL    64      // m-rows per slice (1024 / 16)

typedef float vf4 __attribute__((ext_vector_type(4)));

__device__ __forceinline__ float dot4v(vf4 a, const float4& b) {
    return a.x*b.x + a.y*b.y + a.z*b.z + a.w*b.w;
}

template<int CTRL>
__device__ __forceinline__ float dpp_xadd(float x) {
    union { float f; int i; } u, v;
    u.f = x;
    v.i = __builtin_amdgcn_mov_dpp(u.i, CTRL, 0xf, 0xf, false);
    return x + v.f;
}

__device__ __forceinline__ float sum16(float x) {
    x = dpp_xadd<0xB1>(x);   // quad_perm xor1
    x = dpp_xadd<0x4E>(x);   // quad_perm xor2
    x = dpp_xadd<0x141>(x);  // row_half_mirror
    x = dpp_xadd<0x140>(x);  // row_mirror
    return x;
}

__global__ __launch_bounds__(256, 4) void fused_hg_kernel(
    const float* __restrict__ A_real,
    const float* __restrict__ A_imag,
    const float* __restrict__ W_v,       // row 0 = v; rows 1.. = W (1024 x 256)
    const float* __restrict__ h_d_real,
    const float* __restrict__ h_d_imag,
    float* __restrict__ part_re,         // [128][16][128] = [k][slice][c]
    float* __restrict__ part_im,
    float* __restrict__ out)             // zero-init by block 0
{
    const int kp    = blockIdx.x >> 4;   // 0..63 -> users kp and kp+64
    const int slice = blockIdx.x & 15;   // 0..15 (m-slice of 64)
    const int t     = threadIdx.x;       // 0..255
    const int lane  = t & 63;
    const int wv    = t >> 6;            // wave 0..3
    const int sub   = lane & 15;         // chunk within row (16 lanes/row)
    const int rsub  = lane >> 4;         // row within quad (0..3)
    const int k0 = kp, k1 = kp + 64;

    if (blockIdx.x == 0 && t == 0) *out = 0.f;   // replaces memset dispatch

    __shared__ float sh_re[2][MSL], sh_im[2][MSL];

    const float4 vr0 = ((const float4*)W_v)[sub];
    const float4 vr1 = ((const float4*)W_v)[sub + 16];
    const float4 vi0 = ((const float4*)W_v)[32 + sub];
    const float4 vi1 = ((const float4*)W_v)[48 + sub];

    // ---- phase 1: h = h_d + A·v for this block's 128 rows (2 users x 64 m) ----
    // 4 waves x 4 iterations x 8-row tiles = 128 rows. 2-deep pipeline.
    const int row0 = wv * 32 + rsub;     // iter it -> row0 + it*8
    {
        // prologue: issue iter-0 loads
        int row = row0;
        int u = row >> 6, ml = row & 63;
        size_t rb = (size_t)(u ? k1 : k0) * 1024 + (size_t)slice * MSL + ml;
        const vf4* Ar = (const vf4*)(A_real + rb * 128);
        const vf4* Ai = (const vf4*)(A_imag + rb * 128);
        vf4 a0 = __builtin_nontemporal_load(Ar + sub);
        vf4 a1 = __builtin_nontemporal_load(Ar + sub + 16);
        vf4 b0 = __builtin_nontemporal_load(Ai + sub);
        vf4 b1 = __builtin_nontemporal_load(Ai + sub + 16);
        vf4 c0 = __builtin_nontemporal_load(Ar + 128 + sub);
        vf4 c1 = __builtin_nontemporal_load(Ar + 128 + sub + 16);
        vf4 d0 = __builtin_nontemporal_load(Ai + 128 + sub);
        vf4 d1 = __builtin_nontemporal_load(Ai + 128 + sub + 16);

        #pragma unroll
        for (int it = 0; it < 4; ++it) {
            // current-iteration row bookkeeping
            row = row0 + it * 8;
            u = row >> 6; ml = row & 63;
            rb = (size_t)(u ? k1 : k0) * 1024 + (size_t)slice * MSL + ml;

            // prefetch next iteration's 8 loads before consuming current data
            vf4 na0, na1, nb0, nb1, nc0, nc1, nd0, nd1;
            if (it < 3) {
                const int nrow = row + 8;
                const int nu = nrow >> 6, nml = nrow & 63;
                const size_t nrb = (size_t)(nu ? k1 : k0) * 1024 + (size_t)slice * MSL + nml;
                const vf4* nAr = (const vf4*)(A_real + nrb * 128);
                const vf4* nAi = (const vf4*)(A_imag + nrb * 128);
                na0 = __builtin_nontemporal_load(nAr + sub);
                na1 = __builtin_nontemporal_load(nAr + sub + 16);
                nb0 = __builtin_nontemporal_load(nAi + sub);
                nb1 = __builtin_nontemporal_load(nAi + sub + 16);
                nc0 = __builtin_nontemporal_load(nAr + 128 + sub);
                nc1 = __builtin_nontemporal_load(nAr + 128 + sub + 16);
                nd0 = __builtin_nontemporal_load(nAi + 128 + sub);
                nd1 = __builtin_nontemporal_load(nAi + 128 + sub + 16);
            }

            float p_re = dot4v(a0, vr0) + dot4v(a1, vr1) - dot4v(b0, vi0) - dot4v(b1, vi1);
            float p_im = dot4v(b0, vr0) + dot4v(b1, vr1) + dot4v(a0, vi0) + dot4v(a1, vi1);
            float q_re = dot4v(c0, vr0) + dot4v(c1, vr1) - dot4v(d0, vi0) - dot4v(d1, vi1);
            float q_im = dot4v(d0, vr0) + dot4v(d1, vr1) + dot4v(c0, vi0) + dot4v(c1, vi1);

            p_re = sum16(p_re);
            p_im = sum16(p_im);
            q_re = sum16(q_re);
            q_im = sum16(q_im);

            if (sub == 0) {
                sh_re[u][ml]     = h_d_real[rb]     + p_re;
                sh_im[u][ml]     = h_d_imag[rb]     + p_im;
                sh_re[u][ml + 4] = h_d_real[rb + 4] + q_re;
                sh_im[u][ml + 4] = h_d_imag[rb + 4] + q_im;
            }

            if (it < 3) {
                a0 = na0; a1 = na1; b0 = nb0; b1 = nb1;
                c0 = nc0; c1 = nc1; d0 = nd0; d1 = nd1;
            }
        }
    }
    __syncthreads();

    // ---- phase 2: partial g = h @ W over this m-slice; 2 users share W reads ----
    const int c4  = t & 31;              // column group (4 cols each)
    const int seg = t >> 5;              // m-subrange (8 rows each)
    const float* Wb = W_v + 256 + (size_t)(slice * MSL) * 256;
    float4 gre0 = {0,0,0,0}, gim0 = {0,0,0,0};
    float4 gre1 = {0,0,0,0}, gim1 = {0,0,0,0};
    const int m0 = seg * 8;
    #pragma unroll
    for (int m = m0; m < m0 + 8; ++m) {
        const float4* Wr4 = (const float4*)(Wb + m * 256);
        float4 wr = Wr4[c4];
        float4 wi = Wr4[c4 + 32];
        float hr0 = sh_re[0][m], hi0 = sh_im[0][m];
        float hr1 = sh_re[1][m], hi1 = sh_im[1][m];
        gre0.x = fmaf(hr0, wr.x, fmaf(-hi0, wi.x, gre0.x));
        gre0.y = fmaf(hr0, wr.y, fmaf(-hi0, wi.y, gre0.y));
        gre0.z = fmaf(hr0, wr.z, fmaf(-hi0, wi.z, gre0.z));
        gre0.w = fmaf(hr0, wr.w, fmaf(-hi0, wi.w, gre0.w));
        gim0.x = fmaf(hr0, wi.x, fmaf(hi0, wr.x, gim0.x));
        gim0.y = fmaf(hr0, wi.y, fmaf(hi0, wr.y, gim0.y));
        gim0.z = fmaf(hr0, wi.z, fmaf(hi0, wr.z, gim0.z));
        gim0.w = fmaf(hr0, wi.w, fmaf(hi0, wr.w, gim0.w));
        gre1.x = fmaf(hr1, wr.x, fmaf(-hi1, wi.x, gre1.x));
        gre1.y = fmaf(hr1, wr.y, fmaf(-hi1, wi.y, gre1.y));
        gre1.z = fmaf(hr1, wr.z, fmaf(-hi1, wi.z, gre1.z));
        gre1.w = fmaf(hr1, wr.w, fmaf(-hi1, wi.w, gre1.w));
        gim1.x = fmaf(hr1, wi.x, fmaf(hi1, wr.x, gim1.x));
        gim1.y = fmaf(hr1, wi.y, fmaf(hi1, wr.y, gim1.y));
        gim1.z = fmaf(hr1, wi.z, fmaf(hi1, wr.z, gim1.z));
        gim1.w = fmaf(hr1, wi.w, fmaf(hi1, wr.w, gim1.w));
    }

    __shared__ float4 s_re[2][256], s_im[2][256];
    s_re[0][t] = gre0; s_im[0][t] = gim0;
    s_re[1][t] = gre1; s_im[1][t] = gim1;
    __syncthreads();
    if (t < 64) {
        const int u  = t >> 5;          // user half (0 -> k0, 1 -> k1)
        const int cg = t & 31;          // column group
        float4 r = s_re[u][cg], i = s_im[u][cg];
        #pragma unroll
        for (int s = 1; s < 8; ++s) {
            float4 rr = s_re[u][s * 32 + cg], ii = s_im[u][s * 32 + cg];
            r.x += rr.x; r.y += rr.y; r.z += rr.z; r.w += rr.w;
            i.x += ii.x; i.y += ii.y; i.z += ii.z; i.w += ii.w;
        }
        const int k = (u == 0) ? k0 : k1;
        float4* pr = (float4*)(part_re + ((size_t)k * NSLICE + slice) * 128);
        float4* pi = (float4*)(part_im + ((size_t)k * NSLICE + slice) * 128);
        pr[cg] = r;
        pi[cg] = i;
    }
}

__global__ __launch_bounds__(256) void rate_kernel(
    const float* __restrict__ part_re,
    const float* __restrict__ part_im,
    float* __restrict__ out)
{
    const int k    = blockIdx.x;     // 0..127
    const int t    = threadIdx.x;    // 0..255
    const int c    = t & 127;
    const int half = t >> 7;         // slice-range half (8 slices each)

    const float* br = part_re + (size_t)k * (NSLICE * 128);
    const float* bi = part_im + (size_t)k * (NSLICE * 128);

    float gr = 0.f, gi = 0.f;
    #pragma unroll
    for (int s = half * 8; s < half * 8 + 8; ++s) {
        gr += br[s * 128 + c];
        gi += bi[s * 128 + c];
    }

    __shared__ float rr[256], ri[256];
    rr[t] = gr; ri[t] = gi;
    __syncthreads();

    __shared__ float s_sig;
    __shared__ float s_w[2];
    if (t < 128) {
        gr = rr[t] + rr[t + 128];
        gi = ri[t] + ri[t + 128];
        float mag = sqrtf(gr * gr + gi * gi);
        if (c == k) s_sig = mag;
        float v = mag;
        #pragma unroll
        for (int off = 32; off > 0; off >>= 1) v += __shfl_xor(v, off);
        if ((c & 63) == 0) s_w[c >> 6] = v;
    }
    __syncthreads();

    if (t == 0) {
        float total  = s_w[0] + s_w[1];
        float interf = total - s_sig;
        float R      = s_sig / (interf + 1e-11f);   // N0 = 10^(-80/10)/1000
        atomicAdd(out, -R * 1e6f);
    }
}

extern "C" void kernel_launch(void* const* d_in, const int* in_sizes, int n_in,
                              void* d_out, int out_size, void* d_ws, size_t ws_size,
                              hipStream_t stream) {
    const float* W_v      = (const float*)d_in[0];
    const float* A_real   = (const float*)d_in[1];
    const float* A_imag   = (const float*)d_in[2];
    const float* h_d_real = (const float*)d_in[3];
    const float* h_d_imag = (const float*)d_in[4];
    float* out  = (float*)d_out;

    float* part_re = (float*)d_ws;                   // 128*16*128 floats
    float* part_im = part_re + 128 * NSLICE * 128;   // 128*16*128 floats

    // 64 user-pairs x 16 m-slices = 1024 blocks (exactly 4 blocks/CU):
    // phase 1 streams A (134 MB) into per-block h, phase 2 does the W-GEMM.
    fused_hg_kernel<<<1024, 256, 0, stream>>>(A_real, A_imag, W_v,
                                              h_d_real, h_d_imag,
                                              part_re, part_im, out);
    rate_kernel<<<128, 256, 0, stream>>>(part_re, part_im, out);
}

// Round 3
// 153.661 us; speedup vs baseline: 1.0230x; 1.0230x over previous
//
#include <hip/hip_runtime.h>

// K=128 users, M=1024, N=C=128.
// Fused kernel (R1 structure — compiler-scheduled phase 1; explicit SW
//   pipelining measured -3us regression in R2 and is reverted):
//   each block (kp, slice) computes h = h_d + A·v for its own 2 users x
//   64 m-rows (nontemporal dwordx4, DPP sum16), stores h to LDS, then runs
//   the partial g = h @ W GEMM for that slice.
// rate_kernel (R2 improvement, kept): partials laid out [k][slice][c]
//   (contiguous 16KB per user); 256 threads split the 16-slice reduction
//   8+8 to halve the dependent load chain.

#define NSLICE 16
#define MSL    64      // m-rows per slice (1024 / 16)

typedef float vf4 __attribute__((ext_vector_type(4)));

__device__ __forceinline__ float dot4v(vf4 a, const float4& b) {
    return a.x*b.x + a.y*b.y + a.z*b.z + a.w*b.w;
}

template<int CTRL>
__device__ __forceinline__ float dpp_xadd(float x) {
    union { float f; int i; } u, v;
    u.f = x;
    v.i = __builtin_amdgcn_mov_dpp(u.i, CTRL, 0xf, 0xf, false);
    return x + v.f;
}

__device__ __forceinline__ float sum16(float x) {
    x = dpp_xadd<0xB1>(x);   // quad_perm xor1
    x = dpp_xadd<0x4E>(x);   // quad_perm xor2
    x = dpp_xadd<0x141>(x);  // row_half_mirror
    x = dpp_xadd<0x140>(x);  // row_mirror
    return x;
}

__global__ __launch_bounds__(256, 4) void fused_hg_kernel(
    const float* __restrict__ A_real,
    const float* __restrict__ A_imag,
    const float* __restrict__ W_v,       // row 0 = v; rows 1.. = W (1024 x 256)
    const float* __restrict__ h_d_real,
    const float* __restrict__ h_d_imag,
    float* __restrict__ part_re,         // [128][16][128] = [k][slice][c]
    float* __restrict__ part_im,
    float* __restrict__ out)             // zero-init by block 0
{
    const int kp    = blockIdx.x >> 4;   // 0..63 -> users kp and kp+64
    const int slice = blockIdx.x & 15;   // 0..15 (m-slice of 64)
    const int t     = threadIdx.x;       // 0..255
    const int lane  = t & 63;
    const int wv    = t >> 6;            // wave 0..3
    const int sub   = lane & 15;         // chunk within row (16 lanes/row)
    const int rsub  = lane >> 4;         // row within quad (0..3)
    const int k0 = kp, k1 = kp + 64;

    if (blockIdx.x == 0 && t == 0) *out = 0.f;   // replaces memset dispatch

    __shared__ float sh_re[2][MSL], sh_im[2][MSL];

    const float4 vr0 = ((const float4*)W_v)[sub];
    const float4 vr1 = ((const float4*)W_v)[sub + 16];
    const float4 vi0 = ((const float4*)W_v)[32 + sub];
    const float4 vi1 = ((const float4*)W_v)[48 + sub];

    // ---- phase 1: h = h_d + A·v for this block's 128 rows (2 users x 64 m) ----
    // 4 waves x 4 iterations x 8-row tiles = 128 rows. Compiler-scheduled.
    #pragma unroll
    for (int it = 0; it < 4; ++it) {
        const int row = (wv * 4 + it) * 8 + rsub;   // 0..127 (tile-aligned, never straddles users)
        const int u   = row >> 6;                   // user half
        const int ml  = row & 63;                   // m within slice
        const int k   = u ? k1 : k0;
        const size_t rb = (size_t)k * 1024 + (size_t)slice * MSL + ml;
        const vf4* Ar0 = (const vf4*)(A_real + rb * 128);
        const vf4* Ai0 = (const vf4*)(A_imag + rb * 128);

        // rows rb (p) and rb+4 (q); non-temporal: single-use stream
        const vf4 a0 = __builtin_nontemporal_load(Ar0 + sub);
        const vf4 a1 = __builtin_nontemporal_load(Ar0 + sub + 16);
        const vf4 b0 = __builtin_nontemporal_load(Ai0 + sub);
        const vf4 b1 = __builtin_nontemporal_load(Ai0 + sub + 16);
        const vf4 c0 = __builtin_nontemporal_load(Ar0 + 128 + sub);
        const vf4 c1 = __builtin_nontemporal_load(Ar0 + 128 + sub + 16);
        const vf4 d0 = __builtin_nontemporal_load(Ai0 + 128 + sub);
        const vf4 d1 = __builtin_nontemporal_load(Ai0 + 128 + sub + 16);

        float p_re = dot4v(a0, vr0) + dot4v(a1, vr1) - dot4v(b0, vi0) - dot4v(b1, vi1);
        float p_im = dot4v(b0, vr0) + dot4v(b1, vr1) + dot4v(a0, vi0) + dot4v(a1, vi1);
        float q_re = dot4v(c0, vr0) + dot4v(c1, vr1) - dot4v(d0, vi0) - dot4v(d1, vi1);
        float q_im = dot4v(d0, vr0) + dot4v(d1, vr1) + dot4v(c0, vi0) + dot4v(c1, vi1);

        p_re = sum16(p_re);
        p_im = sum16(p_im);
        q_re = sum16(q_re);
        q_im = sum16(q_im);

        if (sub == 0) {
            sh_re[u][ml]     = h_d_real[rb]     + p_re;
            sh_im[u][ml]     = h_d_imag[rb]     + p_im;
            sh_re[u][ml + 4] = h_d_real[rb + 4] + q_re;
            sh_im[u][ml + 4] = h_d_imag[rb + 4] + q_im;
        }
    }
    __syncthreads();

    // ---- phase 2: partial g = h @ W over this m-slice; 2 users share W reads ----
    const int c4  = t & 31;              // column group (4 cols each)
    const int seg = t >> 5;              // m-subrange (8 rows each)
    const float* Wb = W_v + 256 + (size_t)(slice * MSL) * 256;
    float4 gre0 = {0,0,0,0}, gim0 = {0,0,0,0};
    float4 gre1 = {0,0,0,0}, gim1 = {0,0,0,0};
    const int m0 = seg * 8;
    #pragma unroll
    for (int m = m0; m < m0 + 8; ++m) {
        const float4* Wr4 = (const float4*)(Wb + m * 256);
        float4 wr = Wr4[c4];
        float4 wi = Wr4[c4 + 32];
        float hr0 = sh_re[0][m], hi0 = sh_im[0][m];
        float hr1 = sh_re[1][m], hi1 = sh_im[1][m];
        gre0.x = fmaf(hr0, wr.x, fmaf(-hi0, wi.x, gre0.x));
        gre0.y = fmaf(hr0, wr.y, fmaf(-hi0, wi.y, gre0.y));
        gre0.z = fmaf(hr0, wr.z, fmaf(-hi0, wi.z, gre0.z));
        gre0.w = fmaf(hr0, wr.w, fmaf(-hi0, wi.w, gre0.w));
        gim0.x = fmaf(hr0, wi.x, fmaf(hi0, wr.x, gim0.x));
        gim0.y = fmaf(hr0, wi.y, fmaf(hi0, wr.y, gim0.y));
        gim0.z = fmaf(hr0, wi.z, fmaf(hi0, wr.z, gim0.z));
        gim0.w = fmaf(hr0, wi.w, fmaf(hi0, wr.w, gim0.w));
        gre1.x = fmaf(hr1, wr.x, fmaf(-hi1, wi.x, gre1.x));
        gre1.y = fmaf(hr1, wr.y, fmaf(-hi1, wi.y, gre1.y));
        gre1.z = fmaf(hr1, wr.z, fmaf(-hi1, wi.z, gre1.z));
        gre1.w = fmaf(hr1, wr.w, fmaf(-hi1, wi.w, gre1.w));
        gim1.x = fmaf(hr1, wi.x, fmaf(hi1, wr.x, gim1.x));
        gim1.y = fmaf(hr1, wi.y, fmaf(hi1, wr.y, gim1.y));
        gim1.z = fmaf(hr1, wi.z, fmaf(hi1, wr.z, gim1.z));
        gim1.w = fmaf(hr1, wi.w, fmaf(hi1, wr.w, gim1.w));
    }

    __shared__ float4 s_re[2][256], s_im[2][256];
    s_re[0][t] = gre0; s_im[0][t] = gim0;
    s_re[1][t] = gre1; s_im[1][t] = gim1;
    __syncthreads();
    if (t < 64) {
        const int u  = t >> 5;          // user half (0 -> k0, 1 -> k1)
        const int cg = t & 31;          // column group
        float4 r = s_re[u][cg], i = s_im[u][cg];
        #pragma unroll
        for (int s = 1; s < 8; ++s) {
            float4 rr = s_re[u][s * 32 + cg], ii = s_im[u][s * 32 + cg];
            r.x += rr.x; r.y += rr.y; r.z += rr.z; r.w += rr.w;
            i.x += ii.x; i.y += ii.y; i.z += ii.z; i.w += ii.w;
        }
        const int k = (u == 0) ? k0 : k1;
        float4* pr = (float4*)(part_re + ((size_t)k * NSLICE + slice) * 128);
        float4* pi = (float4*)(part_im + ((size_t)k * NSLICE + slice) * 128);
        pr[cg] = r;
        pi[cg] = i;
    }
}

__global__ __launch_bounds__(256) void rate_kernel(
    const float* __restrict__ part_re,
    const float* __restrict__ part_im,
    float* __restrict__ out)
{
    const int k    = blockIdx.x;     // 0..127
    const int t    = threadIdx.x;    // 0..255
    const int c    = t & 127;
    const int half = t >> 7;         // slice-range half (8 slices each)

    const float* br = part_re + (size_t)k * (NSLICE * 128);
    const float* bi = part_im + (size_t)k * (NSLICE * 128);

    float gr = 0.f, gi = 0.f;
    #pragma unroll
    for (int s = half * 8; s < half * 8 + 8; ++s) {
        gr += br[s * 128 + c];
        gi += bi[s * 128 + c];
    }

    __shared__ float rr[256], ri[256];
    rr[t] = gr; ri[t] = gi;
    __syncthreads();

    __shared__ float s_sig;
    __shared__ float s_w[2];
    if (t < 128) {
        gr = rr[t] + rr[t + 128];
        gi = ri[t] + ri[t + 128];
        float mag = sqrtf(gr * gr + gi * gi);
        if (c == k) s_sig = mag;
        float v = mag;
        #pragma unroll
        for (int off = 32; off > 0; off >>= 1) v += __shfl_xor(v, off);
        if ((c & 63) == 0) s_w[c >> 6] = v;
    }
    __syncthreads();

    if (t == 0) {
        float total  = s_w[0] + s_w[1];
        float interf = total - s_sig;
        float R      = s_sig / (interf + 1e-11f);   // N0 = 10^(-80/10)/1000
        atomicAdd(out, -R * 1e6f);
    }
}

extern "C" void kernel_launch(void* const* d_in, const int* in_sizes, int n_in,
                              void* d_out, int out_size, void* d_ws, size_t ws_size,
                              hipStream_t stream) {
    const float* W_v      = (const float*)d_in[0];
    const float* A_real   = (const float*)d_in[1];
    const float* A_imag   = (const float*)d_in[2];
    const float* h_d_real = (const float*)d_in[3];
    const float* h_d_imag = (const float*)d_in[4];
    float* out  = (float*)d_out;

    float* part_re = (float*)d_ws;                   // 128*16*128 floats
    float* part_im = part_re + 128 * NSLICE * 128;   // 128*16*128 floats

    // 64 user-pairs x 16 m-slices = 1024 blocks (exactly 4 blocks/CU):
    // phase 1 streams A (134 MB) into per-block h, phase 2 does the W-GEMM.
    fused_hg_kernel<<<1024, 256, 0, stream>>>(A_real, A_imag, W_v,
                                              h_d_real, h_d_imag,
                                              part_re, part_im, out);
    rate_kernel<<<128, 256, 0, stream>>>(part_re, part_im, out);
}